// Round 21
// baseline (494.460 us; speedup 1.0000x reference)
//
#include <hip/hip_runtime.h>
#include <hip/hip_bf16.h>

// BayesianKAN: 3 layers of  out[b,o] = sum_{i,k} B-spline-basis(x[b,i])[k] * cm[o,i,k]
// == GEMM (M=8192, N=OUT, K=IN*16) with generated A-operand, plus KL scalar.
// Numerics (validated R4): f16 MFMA; L0 2-term A-split, L1/L2 1-term.
// R5: B fragment-direct from pre-swizzled Bsw; A gen 1x into LDS. R7: dbuf A +
// reg prefetch, 1 barrier/kstep: 482 total. R8/R9/R10 (REV): barrier-drain,
// reg-built-A, launch_bounds(,3) all failed. R11: 64x128 tile resource diet ->
// occupancy 25->42%, VGPR 48, total 461 (BEST). KEY: +70% occupancy gave only
// -4% wall -> NOT TLP-bound. Pipes all <60% busy -> per-kstep serialization
// (ds_read->MFMA->eval->ds_write->barrier chain, 32 barriers/block) is the cap.
// R12: halve sync cadence. 4 A-buffers (buf = k%4), period = 2 ksteps, ONE
// barrier per period (reads bufs pair(t), writes other pair -> race-free both
// directions). 32 MFMA per barrier; B-prefetch slack 2x. L0 keeps R11 path
// (P2=false) as an in-run CONTROL: if L1/L2 move and L0 doesn't, the delta is
// the cadence. Per-acc accumulation order unchanged -> bitwise-same output.

typedef __attribute__((ext_vector_type(8))) _Float16 f16x8;  // 8 f16 in 4 VGPRs
typedef __attribute__((ext_vector_type(4))) float float4v;   // MFMA accumulator
typedef unsigned short ushort_t;

__device__ __forceinline__ ushort_t f2h(float f) {
  _Float16 h = (_Float16)f;                 // RTE
  return *(ushort_t*)&h;
}
__device__ __forceinline__ float h2f(ushort_t u) {
  return (float)*(_Float16*)&u;
}

// Cubic B-spline (n_basis=16, clamped uniform knots: 13 cells of width 1/13).
__device__ __forceinline__ void bspline_w4(float x, int& k0, float w[4]) {
  const float XMAX = 1.0f - 1e-6f;
  float xe = fminf(fmaxf(x, 0.0f), XMAX);
  int cell = (int)(xe * 13.0f);
  cell = cell > 12 ? 12 : cell;
  k0 = cell;
  int j = cell + 3;                 // knot span, 3..15
  const float s = 1.0f / 13.0f;
  int cjm2 = max(j - 5, 0);
  int cjm1 = max(j - 4, 0);
  int cj   = j - 3;
  int cj1  = j - 2;
  int cj2  = min(j - 1, 13);
  int cj3  = min(j, 13);
  float tjm1 = cjm1 * s, tj = cj * s;
  float tjm2 = cjm2 * s;
  float tj1 = cj1 * s, tj2 = cj2 * s, tj3 = cj3 * s;
  float left1 = xe - tj, left2 = xe - tjm1, left3 = xe - tjm2;
  float right1 = tj1 - xe, right2 = tj2 - xe, right3 = tj3 - xe;
#define INV3(d) ((d) == 1 ? 13.0f : ((d) == 2 ? 6.5f : (13.0f / 3.0f)))
  float i10 = INV3(cj1 - cj);
  float i20 = INV3(cj1 - cjm1), i21 = INV3(cj2 - cj);
  float i30 = INV3(cj1 - cjm2), i31 = INV3(cj2 - cjm1), i32 = INV3(cj3 - cj);
#undef INV3
  float temp = i10;
  float N0 = right1 * temp;
  float N1 = left1 * temp;
  temp = N0 * i20;
  N0 = right1 * temp;
  float saved = left2 * temp;
  temp = N1 * i21;
  N1 = saved + right2 * temp;
  float N2 = left1 * temp;
  temp = N0 * i30;
  N0 = right1 * temp;
  saved = left3 * temp;
  temp = N1 * i31;
  N1 = saved + right2 * temp;
  saved = left2 * temp;
  temp = N2 * i32;
  N2 = saved + right3 * temp;
  float N3 = left1 * temp;
  w[0] = N0; w[1] = N1; w[2] = N2; w[3] = N3;
}

// Fused basis-gen + GEMM. Tile 64x128, BK=64 (4 feats x 16 basis), 256 thr =
// 4 waves 1x4, wave tile 64x32 (4x2 frags of f32_16x16x32_f16).
// A staged via multi-buffered LDS; B fragment-direct global->VGPR, prefetched.
// blockIdx.z = split-K; partials atomicAdd into pre-zeroed outp.
template <bool SPLIT_A, bool P2>
__global__ __launch_bounds__(256, 4) void kan_layer(
    const float* __restrict__ act, const ushort_t* __restrict__ Bsw,
    float* __restrict__ outp, int IN, int OUT) {
  const int K = IN * 16;
  const int KC = K >> 3;                             // k-chunks of 8
  __shared__ ushort_t Ah[P2 ? 4 : 2][64 * 72];       // stride 72: +8 pad
  __shared__ ushort_t Al[SPLIT_A ? 2 : 1][SPLIT_A ? 64 * 72 : 1];

  const int tid = threadIdx.x;
  const int lane = tid & 63;
  const int wn = tid >> 6;                // 1x4 wave grid (wm == 0)
  const int quad = lane >> 4, l15 = lane & 15;
  const int b0 = blockIdx.x * 64;
  const int n0 = blockIdx.y * 128;
  const int tbase = (n0 >> 4) + wn * 2;   // B row-tile base for this wave

  float4v acc[4][2];
#pragma unroll
  for (int a = 0; a < 4; a++)
#pragma unroll
    for (int b = 0; b < 2; b++) acc[a][b] = (float4v)0.0f;

  const int gm = tid >> 2;            // basis-gen: row 0..63
  const int gf = tid & 3;             // feat 0..3 of this kstep
  const float* xrow = &act[(size_t)(b0 + gm) * IN + gf];

  const ushort_t* bbase[2];
#pragma unroll
  for (int nt = 0; nt < 2; ++nt)
    bbase[nt] = Bsw + (size_t)(tbase + nt) * KC * 128 + lane * 8;

  const int nsteps = K / 64;
  const int chunk = nsteps / gridDim.z;  // 16 or 32 (divisible by 4)
  const int kbeg = blockIdx.z * chunk;
  const int kend = kbeg + chunk;
  const int klast = kend - 1;

// ---- eval spline (VALU) from reg, write one 16-half A segment into BUF ----
#define EVAL_WRITE(BUF, XS)                                                   \
  {                                                                           \
    int k0a; float wa[4];                                                     \
    bspline_w4(XS, k0a, wa);                                                  \
    uint4 z4; z4.x = z4.y = z4.z = z4.w = 0u;                                 \
    ushort_t* arow_h = &Ah[BUF][gm * 72 + gf * 16];                           \
    ((uint4*)arow_h)[0] = z4; ((uint4*)arow_h)[1] = z4;                       \
    _Pragma("unroll")                                                         \
    for (int t = 0; t < 4; ++t) arow_h[k0a + t] = f2h(wa[t]);                 \
    if (SPLIT_A) {                                                            \
      ushort_t* arow_l = &Al[BUF][gm * 72 + gf * 16];                         \
      ((uint4*)arow_l)[0] = z4; ((uint4*)arow_l)[1] = z4;                     \
      _Pragma("unroll")                                                       \
      for (int t = 0; t < 4; ++t)                                             \
        arow_l[k0a + t] = f2h(wa[t] - h2f(f2h(wa[t])));                       \
    }                                                                         \
  }

// ---- ds_read A-frags from buffer BUF, MFMA against B-frag regs BF ----
#define MFMA_STEP(BUF, BF)                                                    \
  _Pragma("unroll")                                                           \
  for (int ks = 0; ks < 2; ++ks) {                                            \
    f16x8 ahf[4], alf[4];                                                     \
    _Pragma("unroll")                                                         \
    for (int mt = 0; mt < 4; ++mt) {                                          \
      int off = (mt * 16 + l15) * 72 + ks * 32 + quad * 8;                    \
      ahf[mt] = *(const f16x8*)&Ah[BUF][off];                                 \
      if (SPLIT_A) alf[mt] = *(const f16x8*)&Al[BUF][off];                    \
    }                                                                         \
    _Pragma("unroll")                                                         \
    for (int mt = 0; mt < 4; ++mt)                                            \
      _Pragma("unroll")                                                       \
      for (int nt = 0; nt < 2; ++nt) {                                        \
        if (SPLIT_A)                                                          \
          acc[mt][nt] = __builtin_amdgcn_mfma_f32_16x16x32_f16(               \
              alf[mt], (BF)[ks][nt], acc[mt][nt], 0, 0, 0);                   \
        acc[mt][nt] = __builtin_amdgcn_mfma_f32_16x16x32_f16(                 \
            ahf[mt], (BF)[ks][nt], acc[mt][nt], 0, 0, 0);                     \
      }                                                                       \
  }

// ---- load B fragments for one kstep into BF regs ----
#define LOAD_B(BF, KP)                                                        \
  _Pragma("unroll")                                                           \
  for (int ks = 0; ks < 2; ++ks)                                              \
    _Pragma("unroll")                                                         \
    for (int nt = 0; nt < 2; ++nt)                                            \
      BF[ks][nt] = *(const f16x8*)&bbase[nt][(size_t)(KP) * 1024 + ks * 512];

  f16x8 bf0[2][2], bf1[2][2];

  if constexpr (!P2) {
    // ---- R11 path (1 barrier/kstep, 2 buffers) — CONTROL for L0 ----
#define KSTEP_BODY(KS, CUR, BFC, BFN, XVC, XVN)                               \
  {                                                                           \
    const int kp1 = ((KS) + 1 <= klast) ? (KS) + 1 : klast;                   \
    const int kp2 = ((KS) + 2 <= klast) ? (KS) + 2 : klast;                   \
    LOAD_B(BFN, kp1);                                                         \
    XVN = xrow[kp2 * 4];                                                      \
    MFMA_STEP(CUR, BFC);                                                      \
    EVAL_WRITE((CUR) ^ 1, XVC);                                               \
    __syncthreads();                                                          \
  }
    LOAD_B(bf0, kbeg);
    float xvP = xrow[kbeg * 4];
    float xv0 = xrow[((kbeg + 1 <= klast) ? kbeg + 1 : klast) * 4];
    float xv1;
    EVAL_WRITE(0, xvP);
    __syncthreads();
    for (int k = kbeg; k < kend; k += 2) {
      KSTEP_BODY(k,     0, bf0, bf1, xv0, xv1);
      KSTEP_BODY(k + 1, 1, bf1, bf0, xv1, xv0);
    }
#undef KSTEP_BODY
  } else {
    // ---- R12 path: 2-kstep periods, 4 buffers, 1 barrier/period ----
    f16x8 bf2[2][2], bf3[2][2];
    LOAD_B(bf0, kbeg);
    LOAD_B(bf1, kbeg + 1);
    float xvA = xrow[kbeg * 4];
    float xvB = xrow[(kbeg + 1) * 4];
    EVAL_WRITE(0, xvA);
    EVAL_WRITE(1, xvB);
    float xvC = xrow[((kbeg + 2 <= klast) ? kbeg + 2 : klast) * 4];
    float xvD = xrow[((kbeg + 3 <= klast) ? kbeg + 3 : klast) * 4];
    __syncthreads();
    for (int k = kbeg; k < kend; k += 4) {
      // even period: MFMA ksteps k,k+1 (bufs 0,1); eval ksteps k+2,k+3 -> bufs 2,3
      {
        const int kp2 = (k + 2 <= klast) ? k + 2 : klast;
        const int kp3 = (k + 3 <= klast) ? k + 3 : klast;
        const int kp4 = (k + 4 <= klast) ? k + 4 : klast;
        const int kp5 = (k + 5 <= klast) ? k + 5 : klast;
        LOAD_B(bf2, kp2);
        LOAD_B(bf3, kp3);
        const float nxA = xrow[kp4 * 4];
        const float nxB = xrow[kp5 * 4];
        MFMA_STEP(0, bf0);
        MFMA_STEP(1, bf1);
        EVAL_WRITE(2, xvC);   // k+2 < kend always (chunk % 4 == 0)
        EVAL_WRITE(3, xvD);
        __syncthreads();
        xvA = nxA; xvB = nxB;
      }
      // odd period: MFMA ksteps k+2,k+3 (bufs 2,3); eval ksteps k+4,k+5 -> bufs 0,1
      {
        const int kp4 = (k + 4 <= klast) ? k + 4 : klast;
        const int kp5 = (k + 5 <= klast) ? k + 5 : klast;
        const int kp6 = (k + 6 <= klast) ? k + 6 : klast;
        const int kp7 = (k + 7 <= klast) ? k + 7 : klast;
        LOAD_B(bf0, kp4);
        LOAD_B(bf1, kp5);
        const float nxC = xrow[kp6 * 4];
        const float nxD = xrow[kp7 * 4];
        MFMA_STEP(2, bf2);
        MFMA_STEP(3, bf3);
        if (k + 4 < kend) {   // final period writes nothing
          EVAL_WRITE(0, xvA);
          EVAL_WRITE(1, xvB);
        }
        __syncthreads();
        xvC = nxC; xvD = nxD;
      }
    }
  }

#undef LOAD_B
#undef MFMA_STEP
#undef EVAL_WRITE

  // ---- epilogue: C/D layout col=lane&15, row=quad*4+reg; split-K atomics ----
#pragma unroll
  for (int mt = 0; mt < 4; ++mt)
#pragma unroll
    for (int nt = 0; nt < 2; ++nt) {
      int col = n0 + wn * 32 + nt * 16 + l15;
#pragma unroll
      for (int r = 0; r < 4; ++r) {
        int row = b0 + mt * 16 + quad * 4 + r;
        atomicAdd(&outp[(size_t)row * OUT + col], acc[mt][nt][r]);
      }
    }
}

// KL accumulation + f16 conversion + fragment-order swizzle, one pass over cm/lv.
// Group = 8 consecutive k of one output row o: dest Bsw[o/16][k/8][o%16][8].
__global__ __launch_bounds__(256) void kl_convert(
    const float* __restrict__ cm, const float* __restrict__ lv,
    ushort_t* __restrict__ bsw, int G /* = IN*2 groups per row */,
    long long ngroups, float* __restrict__ klout) {
  long long i = (long long)blockIdx.x * blockDim.x + threadIdx.x;
  const long long stride = (long long)gridDim.x * blockDim.x;
  float s = 0.0f;
  for (; i < ngroups; i += stride) {
    int o = (int)(i / G);
    int kc = (int)(i - (long long)o * G);
    const float* cp = &cm[i * 8];
    const float* lp = &lv[i * 8];
    unsigned pk[4];
#pragma unroll
    for (int t = 0; t < 4; ++t) {
      float c0 = cp[2 * t], c1 = cp[2 * t + 1];
      float l0 = lp[2 * t], l1 = lp[2 * t + 1];
      pk[t] = (unsigned)f2h(c0) | ((unsigned)f2h(c1) << 16);
      s += 0.5f * (__expf(l0) + c0 * c0 - 1.0f - l0);
      s += 0.5f * (__expf(l1) + c1 * c1 - 1.0f - l1);
    }
    uint4 v; v.x = pk[0]; v.y = pk[1]; v.z = pk[2]; v.w = pk[3];
    size_t doff = (((size_t)(o >> 4) * G + kc) * 16 + (o & 15)) * 8;
    *(uint4*)&bsw[doff] = v;
  }
#pragma unroll
  for (int off = 32; off > 0; off >>= 1) s += __shfl_down(s, off, 64);
  __shared__ float red[4];
  int wv = threadIdx.x >> 6;
  if ((threadIdx.x & 63) == 0) red[wv] = s;
  __syncthreads();
  if (threadIdx.x == 0)
    atomicAdd(klout, red[0] + red[1] + red[2] + red[3]);
}

extern "C" void kernel_launch(void* const* d_in, const int* in_sizes, int n_in,
                              void* d_out, int out_size, void* d_ws, size_t ws_size,
                              hipStream_t stream) {
  const float* x   = (const float*)d_in[0];
  const float* cm0 = (const float*)d_in[1];
  const float* lv0 = (const float*)d_in[2];
  const float* cm1 = (const float*)d_in[3];
  const float* lv1 = (const float*)d_in[4];
  const float* cm2 = (const float*)d_in[5];
  const float* lv2 = (const float*)d_in[6];

  float* out = (float*)d_out;                       // (8192*256) out + 1 KL
  float* klp = out + (size_t)8192 * 256;

  // ws layout (48 MB): acts 2x16MB, swizzled f16 weights 16MB
  char* ws = (char*)d_ws;
  float*    act1 = (float*)(ws);                               // 8192*512 f32
  float*    act2 = (float*)(ws + ((size_t)16 << 20));          // 8192*512 f32
  ushort_t* b0sw = (ushort_t*)(ws + ((size_t)32 << 20));       // 512*256*16 f16
  ushort_t* b1sw = (ushort_t*)(ws + ((size_t)36 << 20));       // 512*512*16 f16
  ushort_t* b2sw = (ushort_t*)(ws + ((size_t)44 << 20));       // 256*512*16 f16

  // zero split-K accumulation targets (act1+act2 contiguous; d_out incl KL)
  hipMemsetAsync(ws, 0, (size_t)32 << 20, stream);
  hipMemsetAsync(d_out, 0, (size_t)out_size * sizeof(float), stream);

  kl_convert<<<2048, 256, 0, stream>>>(cm0, lv0, b0sw, 256 * 2, 512LL * 256 * 2, klp);
  kl_convert<<<2048, 256, 0, stream>>>(cm1, lv1, b1sw, 512 * 2, 512LL * 512 * 2, klp);
  kl_convert<<<2048, 256, 0, stream>>>(cm2, lv2, b2sw, 512 * 2, 256LL * 512 * 2, klp);

  // L0: control (P2=false, R11 path). L1/L2: 2-kstep periods (P2=true).
  // LDS: L0 36864, L1/L2 36864 -> 4 blk/CU everywhere.
  kan_layer<true , false><<<dim3(128, 4, 4), 256, 0, stream>>>(x,    b0sw, act1, 256, 512);
  kan_layer<false, true ><<<dim3(128, 4, 4), 256, 0, stream>>>(act1, b1sw, act2, 512, 512);
  kan_layer<false, true ><<<dim3(128, 2, 8), 256, 0, stream>>>(act2, b2sw, out,  512, 256);
}